// Round 1
// baseline (443.734 us; speedup 1.0000x reference)
//
#include <hip/hip_runtime.h>
#include <math.h>

#define HEADS 6
#define SEQ   2048
#define DIM   768
#define HDIM  128
#define BATCH 4
#define MTOT  (BATCH*SEQ)   // 8192

typedef float  f32x4  __attribute__((ext_vector_type(4)));
typedef __bf16 bf16x8 __attribute__((ext_vector_type(8)));
typedef __bf16 bf16x4 __attribute__((ext_vector_type(4)));
typedef float  f32x4v __attribute__((ext_vector_type(4)));

typedef __attribute__((address_space(3))) void lds_v;
typedef __attribute__((address_space(1))) void gbl_v;

__device__ __forceinline__ f32x4 mfma16(bf16x8 a, bf16x8 b, f32x4 c) {
    return __builtin_amdgcn_mfma_f32_16x16x32_bf16(a, b, c, 0, 0, 0);
}

// ---------------- cast x (f32 -> bf16), 4 elems/thread ----------------
__global__ __launch_bounds__(256) void cast_x_kernel(const float* __restrict__ x,
                                                     __bf16* __restrict__ xb) {
    int i = (blockIdx.x * 256 + threadIdx.x) * 4;
    f32x4v v = *(const f32x4v*)(x + i);
    bf16x4 o;
    o[0] = (__bf16)v[0]; o[1] = (__bf16)v[1];
    o[2] = (__bf16)v[2]; o[3] = (__bf16)v[3];
    *(bf16x4*)(xb + i) = o;
}

// ---------------- transpose weights W[k][n] f32 -> Wt[n][k] bf16 ----------------
__global__ __launch_bounds__(256) void transpose_w_kernel(
    const float* __restrict__ W0, const float* __restrict__ W1,
    const float* __restrict__ W2, const float* __restrict__ W3,
    __bf16* __restrict__ T0, __bf16* __restrict__ T1,
    __bf16* __restrict__ T2, __bf16* __restrict__ T3) {
    __shared__ float tile[32][33];
    const float* W; __bf16* T;
    if      (blockIdx.z == 0) { W = W0; T = T0; }
    else if (blockIdx.z == 1) { W = W1; T = T1; }
    else if (blockIdx.z == 2) { W = W2; T = T2; }
    else                      { W = W3; T = T3; }
    int n0 = blockIdx.x * 32, k0 = blockIdx.y * 32;
    int tx = threadIdx.x & 31, ty = threadIdx.x >> 5;   // ty 0..7
#pragma unroll
    for (int i = 0; i < 4; ++i)
        tile[ty + i*8][tx] = W[(size_t)(k0 + ty + i*8) * DIM + n0 + tx];
    __syncthreads();
#pragma unroll
    for (int i = 0; i < 4; ++i)
        T[(size_t)(n0 + ty + i*8) * DIM + k0 + tx] = (__bf16)tile[tx][ty + i*8];
}

// ---------------- GEMM: out[M,768] = A[M,768] @ Bt[768,768]^T + bias ----------------
// MODE 0: bf16 out [M,N].  MODE 1: f32 out [M,N].  MODE 2: bf16 out transposed
// per-head into Vt[B][H][HD][SEQ].
template<int MODE>
__global__ __launch_bounds__(256) void gemm_bt(const __bf16* __restrict__ A,
                                               const __bf16* __restrict__ Bt,
                                               const float* __restrict__ bias,
                                               void* __restrict__ outp) {
    constexpr int KD = DIM, N = DIM;
    __shared__ __align__(16) __bf16 As[128 * 32];
    __shared__ __align__(16) __bf16 Bs[128 * 32];
    const int tid  = threadIdx.x;
    const int wave = tid >> 6, lane = tid & 63;
    const int l16  = lane & 15, lh = lane >> 4;
    const int bn = blockIdx.x % (N / 128), bm = blockIdx.x / (N / 128);
    const int m0 = bm * 128, n0 = bn * 128;
    const int wr = wave >> 1, wc = wave & 1;
    f32x4 acc[4][4] = {};

    for (int k0 = 0; k0 < KD; k0 += 32) {
#pragma unroll
        for (int ci = 0; ci < 4; ++ci) {
            int c = wave * 4 + ci;          // 0..15, wave-uniform
            int t = c & 7;
            int e = (t * 64 + lane) * 8;    // element in 128x32 tile
            int r = e >> 5, kk = e & 31;
            const __bf16* gp = (c < 8) ? (A  + (size_t)(m0 + r) * KD + k0 + kk)
                                       : (Bt + (size_t)(n0 + r) * KD + k0 + kk);
            __bf16* lp = (c < 8 ? As : Bs) + t * 512;   // wave-uniform
            __builtin_amdgcn_global_load_lds((const gbl_v*)gp, (lds_v*)lp, 16, 0, 0);
        }
        __syncthreads();
        bf16x8 af[4], bfr[4];
#pragma unroll
        for (int i = 0; i < 4; ++i)
            af[i] = *(const bf16x8*)&As[(wr*64 + i*16 + l16) * 32 + lh*8];
#pragma unroll
        for (int j = 0; j < 4; ++j)
            bfr[j] = *(const bf16x8*)&Bs[(wc*64 + j*16 + l16) * 32 + lh*8];
#pragma unroll
        for (int i = 0; i < 4; ++i)
#pragma unroll
            for (int j = 0; j < 4; ++j)
                acc[i][j] = mfma16(af[i], bfr[j], acc[i][j]);
        __syncthreads();
    }

#pragma unroll
    for (int i = 0; i < 4; ++i) {
        int row = m0 + wr*64 + i*16 + lh*4;       // + r
#pragma unroll
        for (int j = 0; j < 4; ++j) {
            int col = n0 + wc*64 + j*16 + l16;
            float bv = bias[col];
            if constexpr (MODE == 0) {
                __bf16* o = (__bf16*)outp;
#pragma unroll
                for (int r = 0; r < 4; ++r)
                    o[(size_t)(row + r) * N + col] = (__bf16)(acc[i][j][r] + bv);
            } else if constexpr (MODE == 1) {
                float* o = (float*)outp;
#pragma unroll
                for (int r = 0; r < 4; ++r)
                    o[(size_t)(row + r) * N + col] = acc[i][j][r] + bv;
            } else {
                // Vt[((b*H + h)*HD + d)*SEQ + l], rows r are consecutive l
                __bf16* o = (__bf16*)outp;
                int bb = row >> 11, ll = row & (SEQ - 1);
                int hh = col >> 7,  dd = col & (HDIM - 1);
                bf16x4 pk;
#pragma unroll
                for (int r = 0; r < 4; ++r) pk[r] = (__bf16)(acc[i][j][r] + bv);
                *(bf16x4*)&o[((size_t)((bb*HEADS + hh) * HDIM + dd)) * SEQ + ll] = pk;
            }
        }
    }
}

// ---------------- flash attention: 1 wave = 16 query rows ----------------
// Q,K: [MTOT, DIM] bf16 (head h at cols h*128..).  Vt: [B][H][HD][SEQ] bf16.
// O: [MTOT, DIM] bf16.  Causal mask: key <= q+1 (tril k=1).
__global__ __launch_bounds__(64) void attn_kernel(const __bf16* __restrict__ Q,
                                                  const __bf16* __restrict__ K,
                                                  const __bf16* __restrict__ Vt,
                                                  __bf16* __restrict__ O) {
    __shared__ __align__(16) __bf16 P[16 * 32];
    const int lane = threadIdx.x;
    const int l16 = lane & 15, lh = lane >> 4;
    const int qt = blockIdx.x & (SEQ / 16 - 1);          // 0..127
    const int h  = (blockIdx.x >> 7) % HEADS;
    const int b  = blockIdx.x / ((SEQ / 16) * HEADS);
    const int q0 = qt * 16;
    const float scale = 0.08838834764831845f;            // 1/sqrt(128)

    bf16x8 qf[4];
    const __bf16* qbase = Q + (size_t)(b*SEQ + q0 + l16) * DIM + h*HDIM + lh*8;
#pragma unroll
    for (int kk = 0; kk < 4; ++kk) qf[kk] = *(const bf16x8*)(qbase + kk*32);

    f32x4 o[8] = {};
    float mx[4]   = {-INFINITY, -INFINITY, -INFINITY, -INFINITY};
    float lsum[4] = {0.f, 0.f, 0.f, 0.f};

    const int nkeys = min(q0 + 17, SEQ);   // max key = q0+15+1
    const int nkb = (nkeys + 31) >> 5;
    const __bf16* kb_base = K + (size_t)(b*SEQ) * DIM + h*HDIM + lh*8;
    const __bf16* v_base  = Vt + ((size_t)(b*HEADS + h) * HDIM) * SEQ;

    for (int kb = 0; kb < nkb; ++kb) {
        const int kbase = kb * 32;
        f32x4 s0 = {}, s1 = {};
        const __bf16* kp0 = kb_base + (size_t)(kbase + l16) * DIM;
        const __bf16* kp1 = kb_base + (size_t)(kbase + 16 + l16) * DIM;
#pragma unroll
        for (int kk = 0; kk < 4; ++kk) {
            s0 = mfma16(qf[kk], *(const bf16x8*)(kp0 + kk*32), s0);
            s1 = mfma16(qf[kk], *(const bf16x8*)(kp1 + kk*32), s1);
        }
        float resc[4];
#pragma unroll
        for (int r = 0; r < 4; ++r) {
            const int q = q0 + lh*4 + r;
            float v0 = (kbase + l16      <= q + 1) ? s0[r]*scale : -INFINITY;
            float v1 = (kbase + 16 + l16 <= q + 1) ? s1[r]*scale : -INFINITY;
            float m = fmaxf(v0, v1);
#pragma unroll
            for (int t = 1; t < 16; t <<= 1) m = fmaxf(m, __shfl_xor(m, t));
            float mnew = fmaxf(mx[r], m);
            resc[r] = __expf(mx[r] - mnew);   // first block: exp(-inf)=0
            float e0 = __expf(v0 - mnew);
            float e1 = __expf(v1 - mnew);
            float rs = e0 + e1;
#pragma unroll
            for (int t = 1; t < 16; t <<= 1) rs += __shfl_xor(rs, t);
            lsum[r] = lsum[r] * resc[r] + rs;
            mx[r] = mnew;
            P[(lh*4 + r) * 32 + l16]      = (__bf16)e0;
            P[(lh*4 + r) * 32 + 16 + l16] = (__bf16)e1;
        }
#pragma unroll
        for (int vg = 0; vg < 8; ++vg)
#pragma unroll
            for (int r = 0; r < 4; ++r) o[vg][r] *= resc[r];
        __syncthreads();   // single wave: forces lgkmcnt drain before cross-lane read
        bf16x8 pa = *(const bf16x8*)&P[l16 * 32 + lh * 8];
#pragma unroll
        for (int vg = 0; vg < 8; ++vg) {
            bf16x8 vf = *(const bf16x8*)(v_base + (size_t)(vg*16 + l16) * SEQ + kbase + lh*8);
            o[vg] = mfma16(pa, vf, o[vg]);
        }
        __syncthreads();   // P reads done before next iteration's writes
    }

#pragma unroll
    for (int vg = 0; vg < 8; ++vg)
#pragma unroll
        for (int r = 0; r < 4; ++r) {
            float val = o[vg][r] / lsum[r];
            O[(size_t)(b*SEQ + q0 + lh*4 + r) * DIM + h*HDIM + vg*16 + l16] = (__bf16)val;
        }
}

// ---------------- launch ----------------
extern "C" void kernel_launch(void* const* d_in, const int* in_sizes, int n_in,
                              void* d_out, int out_size, void* d_ws, size_t ws_size,
                              hipStream_t stream) {
    const float* x  = (const float*)d_in[0];
    const float* Wq = (const float*)d_in[1];
    const float* bq = (const float*)d_in[2];
    const float* Wk = (const float*)d_in[3];
    const float* bk = (const float*)d_in[4];
    const float* Wv = (const float*)d_in[5];
    const float* bv = (const float*)d_in[6];
    const float* Wo = (const float*)d_in[7];
    const float* bo = (const float*)d_in[8];

    char* p = (char*)d_ws;
    const size_t SZ_X = (size_t)MTOT * DIM * 2;   // 12,582,912
    const size_t SZ_W = (size_t)DIM * DIM * 2;    //  1,179,648
    __bf16* xb  = (__bf16*)p; p += SZ_X;
    __bf16* Wtq = (__bf16*)p; p += SZ_W;
    __bf16* Wtk = (__bf16*)p; p += SZ_W;
    __bf16* Wtv = (__bf16*)p; p += SZ_W;
    __bf16* Wto = (__bf16*)p; p += SZ_W;
    __bf16* Qb  = (__bf16*)p; p += SZ_X;
    __bf16* Kb  = (__bf16*)p; p += SZ_X;
    __bf16* Vt  = (__bf16*)p; p += SZ_X;
    __bf16* Ob  = (__bf16*)p; p += SZ_X;

    cast_x_kernel<<<(MTOT * DIM) / 1024, 256, 0, stream>>>(x, xb);
    transpose_w_kernel<<<dim3(DIM/32, DIM/32, 4), 256, 0, stream>>>(
        Wq, Wk, Wv, Wo, Wtq, Wtk, Wtv, Wto);

    const int gemm_grid = (MTOT / 128) * (DIM / 128);   // 384
    gemm_bt<0><<<gemm_grid, 256, 0, stream>>>(xb, Wtq, bq, Qb);
    gemm_bt<0><<<gemm_grid, 256, 0, stream>>>(xb, Wtk, bk, Kb);
    gemm_bt<2><<<gemm_grid, 256, 0, stream>>>(xb, Wtv, bv, Vt);

    attn_kernel<<<BATCH * HEADS * (SEQ / 16), 64, 0, stream>>>(Qb, Kb, Vt, Ob);

    gemm_bt<1><<<gemm_grid, 256, 0, stream>>>(Ob, Wto, bo, (float*)d_out);
}